// Round 1
// baseline (454.086 us; speedup 1.0000x reference)
//
#include <hip/hip_runtime.h>
#include <hip/hip_bf16.h>

// EnhancedProxyNCALoss: B=4096, C=10000, D=128, SCALE=10, alpha=.25, gamma=2,
// k = int(9999*0.3) = 2999.
// Pipeline: prep (inv-norms + zero out) -> chunked [gemm -> select] -> scalar out.

#define BATCH   4096
#define NCLASS  10000
#define EDIM    128
#define KSEL    2999

__device__ __forceinline__ unsigned int tokey(float f) {
    unsigned int b = __float_as_uint(f);
    return (b & 0x80000000u) ? ~b : (b | 0x80000000u);
}
__device__ __forceinline__ float fromkey(unsigned int k) {
    unsigned int b = (k & 0x80000000u) ? (k ^ 0x80000000u) : ~k;
    return __uint_as_float(b);
}

// ---------------------------------------------------------------- prep ------
// One wave per row: proxies rows [0,10000), embeddings rows [10000,14096).
// inv_e folds SCALE=10. Also zeroes d_out (harness poisons it to 0xAA).
__global__ __launch_bounds__(256) void prep_kernel(
    const float* __restrict__ emb, const float* __restrict__ px,
    float* __restrict__ inv_e, float* __restrict__ inv_p,
    float* __restrict__ out)
{
    const int tid  = threadIdx.x;
    if (blockIdx.x == 0 && tid == 0) out[0] = 0.0f;
    const int lane = tid & 63;
    const int w    = tid >> 6;
    const int row  = blockIdx.x * 4 + w;   // grid = 3524 -> rows 0..14095

    const float* src;
    float* dst;
    float scale;
    if (row < NCLASS) {
        src = px + (size_t)row * EDIM;  dst = inv_p + row;  scale = 1.0f;
    } else {
        int r = row - NCLASS;
        src = emb + (size_t)r * EDIM;   dst = inv_e + r;    scale = 10.0f;
    }
    float a = src[lane], b = src[lane + 64];
    float ss = a * a + b * b;
    #pragma unroll
    for (int off = 32; off; off >>= 1) ss += __shfl_xor(ss, off);
    if (lane == 0) *dst = scale / fmaxf(sqrtf(ss), 1e-12f);
}

// ---------------------------------------------------------------- gemm ------
// sim[rl][c] = (emb[r]*inv_e[r]) . (px[c]*inv_p[c]),  64x64 tile, K=128 full.
// LDS K-major with XOR swizzle: word(k,r) = k*64 + (r ^ (((k>>2)&15)<<2)).
// Inner-loop b128 reads land 2 addresses/bank (free); staging writes ~4-way.
__device__ __forceinline__ int swz(int k, int r) {
    return (k << 6) + (r ^ (((k >> 2) & 15) << 2));
}

__global__ __launch_bounds__(256) void gemm_kernel(
    const float* __restrict__ emb, const float* __restrict__ px,
    const float* __restrict__ inv_e, const float* __restrict__ inv_p,
    float* __restrict__ sim, int row0)
{
    __shared__ float As[128 * 64];   // 32 KB
    __shared__ float Bs[128 * 64];   // 32 KB

    const int tid = threadIdx.x;
    const int c0  = blockIdx.x * 64;
    const int rl0 = blockIdx.y * 64;        // local row base within chunk
    const int rg0 = row0 + rl0;             // global row base

    // stage A (64 rows x 128), float4 global loads, swizzled scalar LDS writes
    for (int idx = tid; idx < 2048; idx += 256) {
        int r  = idx >> 5;
        int d4 = (idx & 31) << 2;
        float sc = inv_e[rg0 + r];
        float4 v = *(const float4*)(emb + (size_t)(rg0 + r) * EDIM + d4);
        As[swz(d4 + 0, r)] = v.x * sc;
        As[swz(d4 + 1, r)] = v.y * sc;
        As[swz(d4 + 2, r)] = v.z * sc;
        As[swz(d4 + 3, r)] = v.w * sc;
    }
    // stage B (64 proxy rows x 128) with tail guard (c >= 10000 -> zeros)
    for (int idx = tid; idx < 2048; idx += 256) {
        int r  = idx >> 5;
        int d4 = (idx & 31) << 2;
        int c  = c0 + r;
        float4 v = make_float4(0.f, 0.f, 0.f, 0.f);
        float sc = 0.0f;
        if (c < NCLASS) {
            v  = *(const float4*)(px + (size_t)c * EDIM + d4);
            sc = inv_p[c];
        }
        Bs[swz(d4 + 0, r)] = v.x * sc;
        Bs[swz(d4 + 1, r)] = v.y * sc;
        Bs[swz(d4 + 2, r)] = v.z * sc;
        Bs[swz(d4 + 3, r)] = v.w * sc;
    }
    __syncthreads();

    const int tx = tid & 15, ty = tid >> 4;
    float acc[4][4] = {};
    #pragma unroll 4
    for (int k = 0; k < 128; ++k) {
        int s = ((k >> 2) & 15);
        float4 a = *(const float4*)&As[(k << 6) + (((ty ^ s) << 2))];
        float4 b = *(const float4*)&Bs[(k << 6) + (((tx ^ s) << 2))];
        float av[4] = {a.x, a.y, a.z, a.w};
        float bv[4] = {b.x, b.y, b.z, b.w};
        #pragma unroll
        for (int i = 0; i < 4; ++i)
            #pragma unroll
            for (int j = 0; j < 4; ++j)
                acc[i][j] += av[i] * bv[j];
    }

    const int c = c0 + tx * 4;
    if (c + 3 < NCLASS) {
        #pragma unroll
        for (int i = 0; i < 4; ++i) {
            int rl = rl0 + ty * 4 + i;
            *(float4*)(sim + (size_t)rl * NCLASS + c) =
                make_float4(acc[i][0], acc[i][1], acc[i][2], acc[i][3]);
        }
    }
}

// -------------------------------------------------------------- select ------
// One block (256 threads) per batch row. 10000 keys in LDS; exact k-th
// largest via 4-round radix select; exp-sum with exact tie handling.
__global__ __launch_bounds__(256) void select_kernel(
    const float* __restrict__ sim, const int* __restrict__ labels,
    const float* __restrict__ cw, float* __restrict__ out, int row0)
{
    __shared__ unsigned int keys[NCLASS];   // 40000 B
    __shared__ unsigned int hist[256];
    __shared__ float        fred[4];
    __shared__ unsigned int ured[4];
    __shared__ float        s_pos;
    __shared__ unsigned int s_prefix, s_want, s_maxkey;

    const int tid   = threadIdx.x;
    const int rl    = blockIdx.x;
    const int row   = row0 + rl;
    const int label = labels[row];
    const float* srow = sim + (size_t)rl * NCLASS;

    if (tid == 0) { s_prefix = 0u; s_want = KSEL; }

    // load row, convert to monotonic keys, extract pos, mask it to -inf
    unsigned int lmax = 0u;
    for (int i4 = tid; i4 < NCLASS / 4; i4 += 256) {
        float4 v = *(const float4*)(srow + (i4 << 2));
        float f[4] = {v.x, v.y, v.z, v.w};
        #pragma unroll
        for (int j = 0; j < 4; ++j) {
            int idx = (i4 << 2) + j;
            float x = f[j];
            if (idx == label) { s_pos = x; x = -INFINITY; }
            unsigned int k = tokey(x);
            keys[idx] = k;
            lmax = (k > lmax) ? k : lmax;
        }
    }
    #pragma unroll
    for (int off = 32; off; off >>= 1) {
        unsigned int o = __shfl_xor(lmax, off);
        lmax = (o > lmax) ? o : lmax;
    }
    if ((tid & 63) == 0) ured[tid >> 6] = lmax;
    __syncthreads();
    if (tid == 0) {
        unsigned int m01 = (ured[0] > ured[1]) ? ured[0] : ured[1];
        unsigned int m23 = (ured[2] > ured[3]) ? ured[2] : ured[3];
        s_maxkey = (m01 > m23) ? m01 : m23;
    }
    __syncthreads();

    // 4-round MSB-first radix select for the KSEL-th largest key
    for (int shift = 24; shift >= 0; shift -= 8) {
        unsigned int prefix = s_prefix;
        unsigned int want   = s_want;
        unsigned int maskhi = (shift == 24) ? 0u : (0xFFFFFFFFu << (shift + 8));
        hist[tid] = 0u;
        __syncthreads();
        for (int i = tid; i < NCLASS; i += 256) {
            unsigned int k = keys[i];
            if (((k ^ prefix) & maskhi) == 0u)
                atomicAdd(&hist[(k >> shift) & 255], 1u);
        }
        __syncthreads();
        // Kogge-Stone suffix sum over 256 bins
        for (int off = 1; off < 256; off <<= 1) {
            unsigned int v = hist[tid] + ((tid + off < 256) ? hist[tid + off] : 0u);
            __syncthreads();
            hist[tid] = v;
            __syncthreads();
        }
        unsigned int suf  = hist[tid];
        unsigned int sufn = (tid == 255) ? 0u : hist[tid + 1];
        if (suf >= want && sufn < want) {
            s_prefix = prefix | ((unsigned int)tid << shift);
            s_want   = want - sufn;
        }
        __syncthreads();
    }

    const unsigned int Kt = s_prefix;
    const float pos = s_pos;
    float m = fmaxf(fromkey(s_maxkey), pos);

    // fused count-strictly-greater + exp-sum
    float lsum = 0.0f;
    unsigned int lcnt = 0u;
    for (int i = tid; i < NCLASS; i += 256) {
        unsigned int k = keys[i];
        if (k > Kt) { lcnt++; lsum += expf(fromkey(k) - m); }
    }
    #pragma unroll
    for (int off = 32; off; off >>= 1) {
        lsum += __shfl_xor(lsum, off);
        lcnt += __shfl_xor(lcnt, off);
    }
    if ((tid & 63) == 0) { fred[tid >> 6] = lsum; ured[tid >> 6] = lcnt; }
    __syncthreads();

    if (tid == 0) {
        float esum = fred[0] + fred[1] + fred[2] + fred[3];
        unsigned int cnt = ured[0] + ured[1] + ured[2] + ured[3];
        float t = fromkey(Kt);
        float denom = esum + (float)(KSEL - (int)cnt) * expf(t - m) + expf(pos - m);
        float p  = expf(pos - m) / denom;
        float ce = -logf(p + 1e-8f);
        float focal = 0.25f * (1.0f - p) * (1.0f - p) * ce;
        atomicAdd(out, focal * cw[label] * (1.0f / (float)BATCH));
    }
}

// ------------------------------------------------------------ launcher ------
extern "C" void kernel_launch(void* const* d_in, const int* in_sizes, int n_in,
                              void* d_out, int out_size, void* d_ws, size_t ws_size,
                              hipStream_t stream) {
    const float* emb    = (const float*)d_in[0];   // 4096 x 128
    const int*   labels = (const int*)d_in[1];     // 4096
    const float* cw     = (const float*)d_in[2];   // 10000
    const float* px     = (const float*)d_in[3];   // 10000 x 128
    float* out = (float*)d_out;
    float* ws  = (float*)d_ws;

    float* inv_p = ws;             // 10000 floats
    float* inv_e = ws + 10240;     // 4096 floats
    float* sim   = ws + 16384;     // chunk_rows x 10000 floats

    size_t avail = (ws_size > 65536) ? (ws_size - 65536) : 0;
    long long cap = (long long)(avail / ((size_t)NCLASS * 4));
    int chunk = (int)((cap / 64) * 64);
    if (chunk > BATCH) chunk = BATCH;
    if (chunk < 64) chunk = 64;    // assume ws >= ~2.6 MB

    prep_kernel<<<3524, 256, 0, stream>>>(emb, px, inv_e, inv_p, out);

    for (int r0 = 0; r0 < BATCH; r0 += chunk) {
        int rows = (BATCH - r0 < chunk) ? (BATCH - r0) : chunk;
        dim3 ggrid((NCLASS + 63) / 64, rows / 64);
        gemm_kernel<<<ggrid, 256, 0, stream>>>(emb, px, inv_e, inv_p, sim, r0);
        select_kernel<<<rows, 256, 0, stream>>>(sim, labels, cw, out, r0);
    }
}

// Round 2
// 269.038 us; speedup vs baseline: 1.6878x; 1.6878x over previous
//
#include <hip/hip_runtime.h>
#include <hip/hip_bf16.h>

// EnhancedProxyNCALoss: B=4096, C=10000, D=128, SCALE=10, alpha=.25, gamma=2,
// k = int(9999*0.3) = 2999.
// Pipeline: prep (normalize+bf16-convert into ws, zero out) ->
//           bf16 MFMA gemm (sim chunk in ws) -> per-row radix-select epilogue.

#define BATCH   4096
#define NCLASS  10000
#define EDIM    128
#define KSEL    2999

typedef __attribute__((ext_vector_type(8))) short short8;
typedef __attribute__((ext_vector_type(4))) float floatx4;

__device__ __forceinline__ unsigned int tokey(float f) {
    unsigned int b = __float_as_uint(f);
    return (b & 0x80000000u) ? ~b : (b | 0x80000000u);
}
__device__ __forceinline__ float fromkey(unsigned int k) {
    unsigned int b = (k & 0x80000000u) ? (k ^ 0x80000000u) : ~k;
    return __uint_as_float(b);
}
__device__ __forceinline__ unsigned short f2bf(float f) {
    unsigned int u = __float_as_uint(f);
    unsigned int r = (u + 0x7FFFu + ((u >> 16) & 1u)) >> 16;   // RNE
    return (unsigned short)r;
}

// ---------------------------------------------------------------- prep ------
// One wave per row: proxies rows [0,10000) -> px_bf, embeddings rows
// [10000,14096) -> emb_bf (SCALE=10 folded). Butterfly reduce gives all
// lanes the norm; each lane writes its 2 bf16. Also zeroes d_out.
__global__ __launch_bounds__(256) void prep_kernel(
    const float* __restrict__ emb, const float* __restrict__ px,
    unsigned short* __restrict__ px_bf, unsigned short* __restrict__ emb_bf,
    float* __restrict__ out)
{
    const int tid  = threadIdx.x;
    if (blockIdx.x == 0 && tid == 0) out[0] = 0.0f;
    const int lane = tid & 63;
    const int w    = tid >> 6;
    const int row  = blockIdx.x * 4 + w;   // grid = 3524 -> rows 0..14095

    const float* src;
    unsigned short* dst;
    float scale;
    if (row < NCLASS) {
        src = px + (size_t)row * EDIM;  dst = px_bf + (size_t)row * EDIM;  scale = 1.0f;
    } else {
        int r = row - NCLASS;
        src = emb + (size_t)r * EDIM;   dst = emb_bf + (size_t)r * EDIM;   scale = 10.0f;
    }
    float a = src[lane], b = src[lane + 64];
    float ss = a * a + b * b;
    #pragma unroll
    for (int off = 32; off; off >>= 1) ss += __shfl_xor(ss, off);
    float inv = scale / fmaxf(sqrtf(ss), 1e-12f);
    dst[lane]      = f2bf(a * inv);
    dst[lane + 64] = f2bf(b * inv);
}

// ---------------------------------------------------------------- gemm ------
// sim = emb10_hat (rows) . px_hat^T, bf16 MFMA 16x16x32, fp32 accumulate.
// 128x128 output tile, full K=128 staged once. LDS rows padded to 136 bf16
// (272 B) so quad fragment reads are 2-way bank-aliased (free).
#define LDK 136

__global__ __launch_bounds__(256) void gemm_kernel(
    const unsigned short* __restrict__ emb_bf,
    const unsigned short* __restrict__ px_bf,
    float* __restrict__ sim, int row0)
{
    __shared__ __align__(16) unsigned short Als[128 * LDK];  // 34816 B
    __shared__ __align__(16) unsigned short Bls[128 * LDK];  // 34816 B

    const int tid  = threadIdx.x;
    const int lane = tid & 63;
    const int w    = tid >> 6;
    const int c0   = blockIdx.x * 128;
    const int rg0  = row0 + blockIdx.y * 128;

    // stage A: 128 rows x 128 k as 2048 16B chunks (8 bf16), 8 per thread
    #pragma unroll
    for (int i = 0; i < 8; ++i) {
        int c  = tid + i * 256;
        int r  = c >> 4;
        int kc = (c & 15) << 3;
        uint4 v = *(const uint4*)(emb_bf + (size_t)(rg0 + r) * EDIM + kc);
        *(uint4*)(Als + r * LDK + kc) = v;
    }
    // stage B: 128 proxy rows x 128 k, tail-guarded (col >= 10000 -> zeros)
    #pragma unroll
    for (int i = 0; i < 8; ++i) {
        int c  = tid + i * 256;
        int n  = c >> 4;
        int kc = (c & 15) << 3;
        uint4 v = make_uint4(0u, 0u, 0u, 0u);
        if (c0 + n < NCLASS)
            v = *(const uint4*)(px_bf + (size_t)(c0 + n) * EDIM + kc);
        *(uint4*)(Bls + n * LDK + kc) = v;
    }
    __syncthreads();

    // wave (w>>1, w&1) owns a 64x64 quadrant = 4x4 grid of 16x16 tiles
    const int wr = (w >> 1) * 64;
    const int wc = (w & 1) * 64;
    const int fm = lane & 15;        // row/col within 16
    const int fq = lane >> 4;        // quad -> k offset *8

    floatx4 acc[4][4];
    #pragma unroll
    for (int i = 0; i < 4; ++i)
        #pragma unroll
        for (int j = 0; j < 4; ++j)
            acc[i][j] = (floatx4){0.f, 0.f, 0.f, 0.f};

    #pragma unroll
    for (int kk = 0; kk < 4; ++kk) {
        const int kof = kk * 32 + fq * 8;
        short8 a[4], b[4];
        #pragma unroll
        for (int i = 0; i < 4; ++i)
            a[i] = *(const short8*)(Als + (wr + i * 16 + fm) * LDK + kof);
        #pragma unroll
        for (int j = 0; j < 4; ++j)
            b[j] = *(const short8*)(Bls + (wc + j * 16 + fm) * LDK + kof);
        #pragma unroll
        for (int i = 0; i < 4; ++i)
            #pragma unroll
            for (int j = 0; j < 4; ++j)
                acc[i][j] = __builtin_amdgcn_mfma_f32_16x16x32_bf16(
                    a[i], b[j], acc[i][j], 0, 0, 0);
    }

    // epilogue: C/D layout col=lane&15, row=(lane>>4)*4+reg
    const int rl0 = blockIdx.y * 128;
    #pragma unroll
    for (int j = 0; j < 4; ++j) {
        int col = c0 + wc + j * 16 + fm;
        if (col >= NCLASS) continue;
        #pragma unroll
        for (int i = 0; i < 4; ++i) {
            int rbase = rl0 + wr + i * 16 + fq * 4;
            #pragma unroll
            for (int r = 0; r < 4; ++r)
                sim[(size_t)(rbase + r) * NCLASS + col] = acc[i][j][r];
        }
    }
}

// -------------------------------------------------------------- select ------
// One block (256 threads) per batch row. 10000 keys in LDS; exact k-th
// largest via 4-round radix select (round 1 fused into load); per-wave
// histogram replicas; single-wave shuffle suffix-scan.
__global__ __launch_bounds__(256) void select_kernel(
    const float* __restrict__ sim, const int* __restrict__ labels,
    const float* __restrict__ cw, float* __restrict__ out, int row0)
{
    __shared__ __align__(16) unsigned int keys[NCLASS];   // 40000 B
    __shared__ __align__(16) unsigned int hist4[256 * 4]; // 4096 B
    __shared__ __align__(16) unsigned int hist[256];      // 1024 B
    __shared__ float        fred[4];
    __shared__ unsigned int ured[4];
    __shared__ float        s_pos;
    __shared__ unsigned int s_prefix, s_want, s_maxkey;

    const int tid   = threadIdx.x;
    const int lane  = tid & 63;
    const int w     = tid >> 6;
    const int rl    = blockIdx.x;
    const int row   = row0 + rl;
    const int label = labels[row];
    const float* srow = sim + (size_t)rl * NCLASS;

    if (tid == 0) { s_prefix = 0u; s_want = KSEL; }
    { uint4 z = make_uint4(0u,0u,0u,0u); *(uint4*)&hist4[tid * 4] = z; }
    __syncthreads();

    // load row -> keys, fuse round-1 (top byte) histogram, track max
    unsigned int lmax = 0u;
    for (int i4 = tid; i4 < NCLASS / 4; i4 += 256) {
        float4 v = *(const float4*)(srow + (i4 << 2));
        float f[4] = {v.x, v.y, v.z, v.w};
        #pragma unroll
        for (int j = 0; j < 4; ++j) {
            int idx = (i4 << 2) + j;
            float x = f[j];
            if (idx == label) { s_pos = x; x = -INFINITY; }
            unsigned int k = tokey(x);
            keys[idx] = k;
            atomicAdd(&hist4[((k >> 24) << 2) + w], 1u);
            lmax = (k > lmax) ? k : lmax;
        }
    }
    #pragma unroll
    for (int off = 32; off; off >>= 1) {
        unsigned int o = __shfl_xor(lmax, off);
        lmax = (o > lmax) ? o : lmax;
    }
    if (lane == 0) ured[w] = lmax;
    __syncthreads();
    if (tid == 0) {
        unsigned int m01 = (ured[0] > ured[1]) ? ured[0] : ured[1];
        unsigned int m23 = (ured[2] > ured[3]) ? ured[2] : ured[3];
        s_maxkey = (m01 > m23) ? m01 : m23;
    }

    // 4-round MSB-first radix select for the KSEL-th largest key
    for (int shift = 24; shift >= 0; shift -= 8) {
        unsigned int prefix, want;
        if (shift < 24) {
            prefix = s_prefix;
            want   = s_want;
            uint4 z = make_uint4(0u,0u,0u,0u);
            *(uint4*)&hist4[tid * 4] = z;
            __syncthreads();
            unsigned int maskhi = 0xFFFFFFFFu << (shift + 8);
            for (int i = tid; i < NCLASS; i += 256) {
                unsigned int k = keys[i];
                if (((k ^ prefix) & maskhi) == 0u)
                    atomicAdd(&hist4[(((k >> shift) & 255u) << 2) + w], 1u);
            }
            __syncthreads();
        } else {
            prefix = 0u; want = KSEL;
            __syncthreads();   // load-pass atomics + s_maxkey drain
        }
        uint4 hv = *(const uint4*)&hist4[tid * 4];
        hist[tid] = hv.x + hv.y + hv.z + hv.w;
        __syncthreads();
        if (w == 0) {
            uint4 g4 = *(const uint4*)&hist[lane * 4];
            unsigned int g = g4.x + g4.y + g4.z + g4.w;
            unsigned int s = g;
            #pragma unroll
            for (int off = 1; off < 64; off <<= 1) {
                unsigned int v = __shfl_down(s, off);
                if (lane + off < 64) s += v;
            }
            unsigned int above = s - g;        // bins in higher lanes
            unsigned int s3 = above + g4.w;
            unsigned int s2 = s3 + g4.z;
            unsigned int s1 = s2 + g4.y;
            unsigned int s0 = s1 + g4.x;
            hist[lane * 4 + 0] = s0; hist[lane * 4 + 1] = s1;
            hist[lane * 4 + 2] = s2; hist[lane * 4 + 3] = s3;
        }
        __syncthreads();
        unsigned int suf  = hist[tid];
        unsigned int sufn = (tid == 255) ? 0u : hist[tid + 1];
        if (suf >= want && sufn < want) {
            s_prefix = prefix | ((unsigned int)tid << shift);
            s_want   = want - sufn;
        }
        __syncthreads();
    }

    const unsigned int Kt = s_prefix;
    const float pos = s_pos;
    float m = fmaxf(fromkey(s_maxkey), pos);

    // fused count-strictly-greater + exp-sum (ties handled exactly)
    float lsum = 0.0f;
    unsigned int lcnt = 0u;
    for (int i = tid; i < NCLASS; i += 256) {
        unsigned int k = keys[i];
        if (k > Kt) { lcnt++; lsum += __expf(fromkey(k) - m); }
    }
    #pragma unroll
    for (int off = 32; off; off >>= 1) {
        lsum += __shfl_xor(lsum, off);
        lcnt += __shfl_xor(lcnt, off);
    }
    if (lane == 0) { fred[w] = lsum; ured[w] = lcnt; }
    __syncthreads();

    if (tid == 0) {
        float esum = fred[0] + fred[1] + fred[2] + fred[3];
        unsigned int cnt = ured[0] + ured[1] + ured[2] + ured[3];
        float t = fromkey(Kt);
        float denom = esum + (float)(KSEL - (int)cnt) * __expf(t - m) + __expf(pos - m);
        float p  = __expf(pos - m) / denom;
        float ce = -logf(p + 1e-8f);
        float focal = 0.25f * (1.0f - p) * (1.0f - p) * ce;
        atomicAdd(out, focal * cw[label] * (1.0f / (float)BATCH));
    }
}

// ------------------------------------------------------------ launcher ------
extern "C" void kernel_launch(void* const* d_in, const int* in_sizes, int n_in,
                              void* d_out, int out_size, void* d_ws, size_t ws_size,
                              hipStream_t stream) {
    const float* emb    = (const float*)d_in[0];   // 4096 x 128
    const int*   labels = (const int*)d_in[1];     // 4096
    const float* cw     = (const float*)d_in[2];   // 10000
    const float* px     = (const float*)d_in[3];   // 10000 x 128
    float* out = (float*)d_out;
    char*  wsc = (char*)d_ws;

    unsigned short* px_bf  = (unsigned short*)wsc;                 // 10000*128 bf16
    unsigned short* emb_bf = (unsigned short*)(wsc + 2560000);     // 4096*128 bf16
    float*          sim    = (float*)(wsc + 3608576);              // chunk x 10000 f32

    size_t fixed = 3608576;
    size_t avail = (ws_size > fixed) ? (ws_size - fixed) : 0;
    long long cap = (long long)(avail / ((size_t)NCLASS * 4));
    int chunk = (int)((cap / 128) * 128);
    if (chunk > BATCH) chunk = BATCH;
    if (chunk < 128) chunk = 128;   // ws is known to be large enough

    prep_kernel<<<3524, 256, 0, stream>>>(emb, px, px_bf, emb_bf, out);

    for (int r0 = 0; r0 < BATCH; r0 += chunk) {
        int rows = (BATCH - r0 < chunk) ? (BATCH - r0) : chunk;
        dim3 ggrid((NCLASS + 127) / 128, rows / 128);
        gemm_kernel<<<ggrid, 256, 0, stream>>>(emb_bf, px_bf, sim, r0);
        select_kernel<<<rows, 256, 0, stream>>>(sim, labels, cw, out, r0);
    }
}

// Round 3
// 190.115 us; speedup vs baseline: 2.3885x; 1.4151x over previous
//
#include <hip/hip_runtime.h>
#include <hip/hip_bf16.h>

// EnhancedProxyNCALoss: B=4096, C=10000, D=128, SCALE=10, alpha=.25, gamma=2,
// k = int(9999*0.3) = 2999.
// Pipeline: prep (normalize+bf16-convert into ws, zero out) ->
//           bf16 MFMA gemm (sim chunk in ws) -> per-row 16-bit radix-select.

#define BATCH   4096
#define NCLASS  10000
#define EDIM    128
#define KSEL    2999

typedef __attribute__((ext_vector_type(8))) short short8;
typedef __attribute__((ext_vector_type(4))) float floatx4;

__device__ __forceinline__ unsigned int tokey(float f) {
    unsigned int b = __float_as_uint(f);
    return (b & 0x80000000u) ? ~b : (b | 0x80000000u);
}
__device__ __forceinline__ float fromkey(unsigned int k) {
    unsigned int b = (k & 0x80000000u) ? (k ^ 0x80000000u) : ~k;
    return __uint_as_float(b);
}
__device__ __forceinline__ unsigned short f2bf(float f) {
    unsigned int u = __float_as_uint(f);
    unsigned int r = (u + 0x7FFFu + ((u >> 16) & 1u)) >> 16;   // RNE
    return (unsigned short)r;
}

// ---------------------------------------------------------------- prep ------
__global__ __launch_bounds__(256) void prep_kernel(
    const float* __restrict__ emb, const float* __restrict__ px,
    unsigned short* __restrict__ px_bf, unsigned short* __restrict__ emb_bf,
    float* __restrict__ out)
{
    const int tid  = threadIdx.x;
    if (blockIdx.x == 0 && tid == 0) out[0] = 0.0f;
    const int lane = tid & 63;
    const int w    = tid >> 6;
    const int row  = blockIdx.x * 4 + w;   // grid = 3524 -> rows 0..14095

    const float* src;
    unsigned short* dst;
    float scale;
    if (row < NCLASS) {
        src = px + (size_t)row * EDIM;  dst = px_bf + (size_t)row * EDIM;  scale = 1.0f;
    } else {
        int r = row - NCLASS;
        src = emb + (size_t)r * EDIM;   dst = emb_bf + (size_t)r * EDIM;   scale = 10.0f;
    }
    float a = src[lane], b = src[lane + 64];
    float ss = a * a + b * b;
    #pragma unroll
    for (int off = 32; off; off >>= 1) ss += __shfl_xor(ss, off);
    float inv = scale / fmaxf(sqrtf(ss), 1e-12f);
    dst[lane]      = f2bf(a * inv);
    dst[lane + 64] = f2bf(b * inv);
}

// ---------------------------------------------------------------- gemm ------
// sim = emb10_hat . px_hat^T, bf16 MFMA 16x16x32, fp32 acc. 128x128 tile,
// full K=128 staged once; LDS rows padded to 136 bf16 (2-way reads, free).
#define LDK 136

__global__ __launch_bounds__(256) void gemm_kernel(
    const unsigned short* __restrict__ emb_bf,
    const unsigned short* __restrict__ px_bf,
    float* __restrict__ sim, int row0)
{
    __shared__ __align__(16) unsigned short Als[128 * LDK];
    __shared__ __align__(16) unsigned short Bls[128 * LDK];

    const int tid  = threadIdx.x;
    const int lane = tid & 63;
    const int w    = tid >> 6;
    const int c0   = blockIdx.x * 128;
    const int rg0  = row0 + blockIdx.y * 128;

    #pragma unroll
    for (int i = 0; i < 8; ++i) {
        int c  = tid + i * 256;
        int r  = c >> 4;
        int kc = (c & 15) << 3;
        uint4 v = *(const uint4*)(emb_bf + (size_t)(rg0 + r) * EDIM + kc);
        *(uint4*)(Als + r * LDK + kc) = v;
    }
    #pragma unroll
    for (int i = 0; i < 8; ++i) {
        int c  = tid + i * 256;
        int n  = c >> 4;
        int kc = (c & 15) << 3;
        uint4 v = make_uint4(0u, 0u, 0u, 0u);
        if (c0 + n < NCLASS)
            v = *(const uint4*)(px_bf + (size_t)(c0 + n) * EDIM + kc);
        *(uint4*)(Bls + n * LDK + kc) = v;
    }
    __syncthreads();

    const int wr = (w >> 1) * 64;
    const int wc = (w & 1) * 64;
    const int fm = lane & 15;
    const int fq = lane >> 4;

    floatx4 acc[4][4];
    #pragma unroll
    for (int i = 0; i < 4; ++i)
        #pragma unroll
        for (int j = 0; j < 4; ++j)
            acc[i][j] = (floatx4){0.f, 0.f, 0.f, 0.f};

    #pragma unroll
    for (int kk = 0; kk < 4; ++kk) {
        const int kof = kk * 32 + fq * 8;
        short8 a[4], b[4];
        #pragma unroll
        for (int i = 0; i < 4; ++i)
            a[i] = *(const short8*)(Als + (wr + i * 16 + fm) * LDK + kof);
        #pragma unroll
        for (int j = 0; j < 4; ++j)
            b[j] = *(const short8*)(Bls + (wc + j * 16 + fm) * LDK + kof);
        #pragma unroll
        for (int i = 0; i < 4; ++i)
            #pragma unroll
            for (int j = 0; j < 4; ++j)
                acc[i][j] = __builtin_amdgcn_mfma_f32_16x16x32_bf16(
                    a[i], b[j], acc[i][j], 0, 0, 0);
    }

    const int rl0 = blockIdx.y * 128;
    #pragma unroll
    for (int j = 0; j < 4; ++j) {
        int col = c0 + wc + j * 16 + fm;
        if (col >= NCLASS) continue;
        #pragma unroll
        for (int i = 0; i < 4; ++i) {
            int rbase = rl0 + wr + i * 16 + fq * 4;
            #pragma unroll
            for (int r = 0; r < 4; ++r)
                sim[(size_t)(rbase + r) * NCLASS + col] = acc[i][j][r];
        }
    }
}

// -------------------------------------------------------------- select ------
// One block per batch row. 16-bit quantized keys in LDS (20 KB); k-th largest
// 16-bit key via 2-round radix select (round 1 fused into load); final pass
// re-reads sim (L3-hot) for full-precision exp-sum; tie-fill at the bin edge.
// Boundary bin holds ~8 of 10000 keys -> quantization error ~1e-4 relative.
__global__ __launch_bounds__(256) void select_kernel(
    const float* __restrict__ sim, const int* __restrict__ labels,
    const float* __restrict__ cw, float* __restrict__ out, int row0)
{
    __shared__ __align__(16) unsigned short keys16[NCLASS];    // 20000 B
    __shared__ __align__(16) unsigned int   hist9[256 * 9];    // 9216 B
    __shared__ __align__(16) unsigned int   hist[256];         // 1024 B
    __shared__ unsigned int ured[4];
    __shared__ float        s_pos, s_m;
    __shared__ unsigned int s_b1, s_want;

    const int tid   = threadIdx.x;
    const int lane  = tid & 63;
    const int w     = tid >> 6;
    const int rl    = blockIdx.x;
    const int row   = row0 + rl;
    const int label = labels[row];
    const int rep   = lane & 7;
    const float* srow = sim + (size_t)rl * NCLASS;

    #pragma unroll
    for (int i = 0; i < 9; ++i) hist9[tid * 9 + i] = 0u;
    if (tid == 0) s_want = KSEL;
    __syncthreads();

    // ---- pass 1: load row, quantize to 16-bit keys, fused top-byte hist ----
    unsigned int lmax = 0u;
    for (int i4 = tid; i4 < NCLASS / 4; i4 += 256) {
        float4 v = *(const float4*)(srow + (i4 << 2));
        float f[4] = {v.x, v.y, v.z, v.w};
        unsigned int k16[4];
        #pragma unroll
        for (int j = 0; j < 4; ++j) {
            int idx = (i4 << 2) + j;
            float x = f[j];
            if (idx == label) { s_pos = x; x = -INFINITY; }
            unsigned int k = tokey(x);
            lmax = (k > lmax) ? k : lmax;
            k16[j] = k >> 16;
            atomicAdd(&hist9[(k16[j] >> 8) * 9 + rep], 1u);
        }
        uint2 pk;
        pk.x = k16[0] | (k16[1] << 16);
        pk.y = k16[2] | (k16[3] << 16);
        *(uint2*)(keys16 + (i4 << 2)) = pk;
    }
    #pragma unroll
    for (int off = 32; off; off >>= 1) {
        unsigned int o = __shfl_xor(lmax, off);
        lmax = (o > lmax) ? o : lmax;
    }
    if (lane == 0) ured[w] = lmax;
    __syncthreads();
    if (tid == 0) {
        unsigned int m01 = (ured[0] > ured[1]) ? ured[0] : ured[1];
        unsigned int m23 = (ured[2] > ured[3]) ? ured[2] : ured[3];
        unsigned int mk  = (m01 > m23) ? m01 : m23;
        s_m = fmaxf(fromkey(mk), s_pos);
    }

    // ---- two radix rounds over the 16-bit keys ----
    #pragma unroll
    for (int round = 0; round < 2; ++round) {
        if (round == 1) {
            // rebuild histogram on low byte, filtered by chosen top byte
            __syncthreads();
            #pragma unroll
            for (int i = 0; i < 9; ++i) hist9[tid * 9 + i] = 0u;
            __syncthreads();
            const unsigned int b1 = s_b1;
            for (int i2 = tid; i2 < NCLASS / 4; i2 += 256) {
                uint2 pk = *(const uint2*)(keys16 + (i2 << 2));
                unsigned int k0 = pk.x & 0xFFFFu, k1 = pk.x >> 16;
                unsigned int k2 = pk.y & 0xFFFFu, k3 = pk.y >> 16;
                if ((k0 >> 8) == b1) atomicAdd(&hist9[(k0 & 255u) * 9 + rep], 1u);
                if ((k1 >> 8) == b1) atomicAdd(&hist9[(k1 & 255u) * 9 + rep], 1u);
                if ((k2 >> 8) == b1) atomicAdd(&hist9[(k2 & 255u) * 9 + rep], 1u);
                if ((k3 >> 8) == b1) atomicAdd(&hist9[(k3 & 255u) * 9 + rep], 1u);
            }
        }
        __syncthreads();
        unsigned int want = s_want;
        unsigned int hsum = 0u;
        #pragma unroll
        for (int i = 0; i < 9; ++i) hsum += hist9[tid * 9 + i];
        hist[tid] = hsum;
        __syncthreads();
        if (w == 0) {
            uint4 g4 = *(const uint4*)&hist[lane * 4];
            unsigned int g = g4.x + g4.y + g4.z + g4.w;
            unsigned int s = g;
            #pragma unroll
            for (int off = 1; off < 64; off <<= 1) {
                unsigned int v = __shfl_down(s, off);
                if (lane + off < 64) s += v;
            }
            unsigned int above = s - g;
            unsigned int s3 = above + g4.w;
            unsigned int s2 = s3 + g4.z;
            unsigned int s1 = s2 + g4.y;
            unsigned int s0 = s1 + g4.x;
            hist[lane * 4 + 0] = s0; hist[lane * 4 + 1] = s1;
            hist[lane * 4 + 2] = s2; hist[lane * 4 + 3] = s3;
        }
        __syncthreads();
        unsigned int suf  = hist[tid];
        unsigned int sufn = (tid == 255) ? 0u : hist[tid + 1];
        if (suf >= want && sufn < want) {
            if (round == 0) s_b1 = (unsigned int)tid;
            else            s_b1 = (s_b1 << 8) | (unsigned int)tid;
            s_want = want - sufn;   // slots left inside the chosen bin
        }
        __syncthreads();
    }

    const unsigned int K16  = s_b1;     // 2999th-largest 16-bit key
    const unsigned int fill = s_want;   // boundary-bin slots (>=1)
    const float m   = s_m;
    const float pos = s_pos;

    // ---- final pass: full-precision exp-sum over keys strictly above bin ---
    float lsum = 0.0f;
    for (int i4 = tid; i4 < NCLASS / 4; i4 += 256) {
        uint2 pk = *(const uint2*)(keys16 + (i4 << 2));
        float4 v = *(const float4*)(srow + (i4 << 2));
        unsigned int k[4] = {pk.x & 0xFFFFu, pk.x >> 16, pk.y & 0xFFFFu, pk.y >> 16};
        float f[4] = {v.x, v.y, v.z, v.w};
        #pragma unroll
        for (int j = 0; j < 4; ++j)
            if (k[j] > K16) lsum += __expf(f[j] - m);
    }
    #pragma unroll
    for (int off = 32; off; off >>= 1) lsum += __shfl_xor(lsum, off);
    if (lane == 0) ((float*)ured)[w] = lsum;
    __syncthreads();

    if (tid == 0) {
        float* fr = (float*)ured;
        float esum = fr[0] + fr[1] + fr[2] + fr[3];
        float t = fromkey(K16 << 16);
        float denom = esum + (float)fill * __expf(t - m) + __expf(pos - m);
        float p  = __expf(pos - m) / denom;
        float ce = -logf(p + 1e-8f);
        float focal = 0.25f * (1.0f - p) * (1.0f - p) * ce;
        atomicAdd(out, focal * cw[label] * (1.0f / (float)BATCH));
    }
}

// ------------------------------------------------------------ launcher ------
extern "C" void kernel_launch(void* const* d_in, const int* in_sizes, int n_in,
                              void* d_out, int out_size, void* d_ws, size_t ws_size,
                              hipStream_t stream) {
    const float* emb    = (const float*)d_in[0];   // 4096 x 128
    const int*   labels = (const int*)d_in[1];     // 4096
    const float* cw     = (const float*)d_in[2];   // 10000
    const float* px     = (const float*)d_in[3];   // 10000 x 128
    float* out = (float*)d_out;
    char*  wsc = (char*)d_ws;

    unsigned short* px_bf  = (unsigned short*)wsc;                 // 10000*128 bf16
    unsigned short* emb_bf = (unsigned short*)(wsc + 2560000);     // 4096*128 bf16
    float*          sim    = (float*)(wsc + 3608576);              // chunk x 10000 f32

    size_t fixed = 3608576;
    size_t avail = (ws_size > fixed) ? (ws_size - fixed) : 0;
    long long cap = (long long)(avail / ((size_t)NCLASS * 4));
    int chunk = (int)((cap / 128) * 128);
    if (chunk > BATCH) chunk = BATCH;
    if (chunk < 128) chunk = 128;

    prep_kernel<<<3524, 256, 0, stream>>>(emb, px, px_bf, emb_bf, out);

    for (int r0 = 0; r0 < BATCH; r0 += chunk) {
        int rows = (BATCH - r0 < chunk) ? (BATCH - r0) : chunk;
        dim3 ggrid((NCLASS + 127) / 128, rows / 128);
        gemm_kernel<<<ggrid, 256, 0, stream>>>(emb_bf, px_bf, sim, r0);
        select_kernel<<<rows, 256, 0, stream>>>(sim, labels, cw, out, r0);
    }
}

// Round 4
// 173.723 us; speedup vs baseline: 2.6138x; 1.0944x over previous
//
#include <hip/hip_runtime.h>
#include <hip/hip_bf16.h>
#include <hip/hip_fp16.h>

// EnhancedProxyNCALoss: B=4096, C=10000, D=128, SCALE=10, alpha=.25, gamma=2,
// k = int(9999*0.3) = 2999.
// Pipeline: prep (normalize+bf16 into ws, zero out) ->
//           bf16 MFMA gemm writing sim as 16-bit monotonic half-keys ->
//           per-row single-round 2048-bin select + focal epilogue.

#define BATCH   4096
#define NCLASS  10000
#define EDIM    128
#define KSEL    2999
#define LDK     136
#define MLOG    10.0f   // sim <= 10 always (cosine * SCALE) -> safe softmax max

typedef __attribute__((ext_vector_type(8))) short short8;
typedef __attribute__((ext_vector_type(4))) float floatx4;

__device__ __forceinline__ unsigned short f2bf(float f) {
    unsigned int u = __float_as_uint(f);
    unsigned int r = (u + 0x7FFFu + ((u >> 16) & 1u)) >> 16;   // RNE
    return (unsigned short)r;
}
// float -> half (RNE) -> monotonic 16-bit key (order-preserving)
__device__ __forceinline__ unsigned int f2key16(float x) {
    unsigned short hb = __half_as_ushort(__float2half(x));
    return (hb & 0x8000u) ? (unsigned int)(~hb & 0xFFFFu)
                          : (unsigned int)(hb | 0x8000u);
}
__device__ __forceinline__ float key16val(unsigned int k) {
    unsigned short hb = (k & 0x8000u) ? (unsigned short)(k ^ 0x8000u)
                                      : (unsigned short)(~k & 0xFFFFu);
    return __half2float(__ushort_as_half(hb));
}

// ---------------------------------------------------------------- prep ------
__global__ __launch_bounds__(256) void prep_kernel(
    const float* __restrict__ emb, const float* __restrict__ px,
    unsigned short* __restrict__ px_bf, unsigned short* __restrict__ emb_bf,
    float* __restrict__ out)
{
    const int tid  = threadIdx.x;
    if (blockIdx.x == 0 && tid == 0) out[0] = 0.0f;
    const int lane = tid & 63;
    const int w    = tid >> 6;
    const int row  = blockIdx.x * 4 + w;   // grid = 3524 -> rows 0..14095

    const float* src;
    unsigned short* dst;
    float scale;
    if (row < NCLASS) {
        src = px + (size_t)row * EDIM;  dst = px_bf + (size_t)row * EDIM;  scale = 1.0f;
    } else {
        int r = row - NCLASS;
        src = emb + (size_t)r * EDIM;   dst = emb_bf + (size_t)r * EDIM;   scale = 10.0f;
    }
    float a = src[lane], b = src[lane + 64];
    float ss = a * a + b * b;
    #pragma unroll
    for (int off = 32; off; off >>= 1) ss += __shfl_xor(ss, off);
    float inv = scale / fmaxf(sqrtf(ss), 1e-12f);
    dst[lane]      = f2bf(a * inv);
    dst[lane + 64] = f2bf(b * inv);
}

// ---------------------------------------------------------------- gemm ------
// sim = emb10_hat . px_hat^T, bf16 MFMA 16x16x32, fp32 acc, 128x128 tile.
// Epilogue: fp32 -> half -> monotonic key16, LDS transpose (reuse Als),
// coalesced uint4 stores (8 keys / 16 B per lane).
__global__ __launch_bounds__(256) void gemm_kernel(
    const unsigned short* __restrict__ emb_bf,
    const unsigned short* __restrict__ px_bf,
    unsigned short* __restrict__ simk, int row0)
{
    __shared__ __align__(16) unsigned short Als[128 * LDK];
    __shared__ __align__(16) unsigned short Bls[128 * LDK];

    const int tid  = threadIdx.x;
    const int lane = tid & 63;
    const int w    = tid >> 6;
    const int c0   = blockIdx.x * 128;
    const int rg0  = row0 + blockIdx.y * 128;

    #pragma unroll
    for (int i = 0; i < 8; ++i) {
        int c  = tid + i * 256;
        int r  = c >> 4;
        int kc = (c & 15) << 3;
        uint4 v = *(const uint4*)(emb_bf + (size_t)(rg0 + r) * EDIM + kc);
        *(uint4*)(Als + r * LDK + kc) = v;
    }
    #pragma unroll
    for (int i = 0; i < 8; ++i) {
        int c  = tid + i * 256;
        int n  = c >> 4;
        int kc = (c & 15) << 3;
        uint4 v = make_uint4(0u, 0u, 0u, 0u);
        if (c0 + n < NCLASS)
            v = *(const uint4*)(px_bf + (size_t)(c0 + n) * EDIM + kc);
        *(uint4*)(Bls + n * LDK + kc) = v;
    }
    __syncthreads();

    const int wr = (w >> 1) * 64;
    const int wc = (w & 1) * 64;
    const int fm = lane & 15;
    const int fq = lane >> 4;

    floatx4 acc[4][4];
    #pragma unroll
    for (int i = 0; i < 4; ++i)
        #pragma unroll
        for (int j = 0; j < 4; ++j)
            acc[i][j] = (floatx4){0.f, 0.f, 0.f, 0.f};

    #pragma unroll
    for (int kk = 0; kk < 4; ++kk) {
        const int kof = kk * 32 + fq * 8;
        short8 a[4], b[4];
        #pragma unroll
        for (int i = 0; i < 4; ++i)
            a[i] = *(const short8*)(Als + (wr + i * 16 + fm) * LDK + kof);
        #pragma unroll
        for (int j = 0; j < 4; ++j)
            b[j] = *(const short8*)(Bls + (wc + j * 16 + fm) * LDK + kof);
        #pragma unroll
        for (int i = 0; i < 4; ++i)
            #pragma unroll
            for (int j = 0; j < 4; ++j)
                acc[i][j] = __builtin_amdgcn_mfma_f32_16x16x32_bf16(
                    a[i], b[j], acc[i][j], 0, 0, 0);
    }

    __syncthreads();                       // all LDS reads done; reuse Als
    unsigned short* T = Als;               // 128 x LDK key16 tile
    // C/D layout: col = lane&15, row = (lane>>4)*4 + reg
    #pragma unroll
    for (int j = 0; j < 4; ++j) {
        int col = wc + j * 16 + fm;
        #pragma unroll
        for (int i = 0; i < 4; ++i) {
            int rbase = wr + i * 16 + fq * 4;
            #pragma unroll
            for (int r = 0; r < 4; ++r)
                T[(rbase + r) * LDK + col] = (unsigned short)f2key16(acc[i][j][r]);
        }
    }
    __syncthreads();

    const int rl0 = blockIdx.y * 128;
    #pragma unroll
    for (int t = 0; t < 8; ++t) {
        int idx = t * 256 + tid;
        int rowl = idx >> 4;
        int g    = idx & 15;
        int col  = c0 + g * 8;
        if (col < NCLASS) {                // 10000 % 8 == 0 -> group all-valid
            uint4 v = *(const uint4*)(T + rowl * LDK + g * 8);
            *(uint4*)(simk + (size_t)(rl0 + rowl) * NCLASS + col) = v;
        }
    }
}

// -------------------------------------------------------------- select ------
// One block per batch row. key16 row (20 KB) -> LDS with fused 2048-bin
// (11-bit prefix) histogram; register suffix-scan finds boundary bin b;
// single exp pass: exact sum over bins > b, mean-fill inside bin b.
// Boundary-bin value spread <= ~1.6% -> denominator error <= ~0.1%.
__global__ __launch_bounds__(256) void select_kernel(
    const unsigned short* __restrict__ simk, const int* __restrict__ labels,
    const float* __restrict__ cw, float* __restrict__ out, int row0)
{
    __shared__ __align__(16) unsigned short keys[NCLASS];   // 20000 B
    __shared__ __align__(16) unsigned int   hist[2048];     // 8192 B
    __shared__ __align__(16) unsigned int   psum[256];      // 1024 B
    __shared__ float fred[8];
    __shared__ float s_pos;
    __shared__ unsigned int s_b, s_fill, s_cntb;

    const int tid   = threadIdx.x;
    const int lane  = tid & 63;
    const int w     = tid >> 6;
    const int rl    = blockIdx.x;
    const int label = labels[row0 + rl];
    const unsigned short* srow = simk + (size_t)rl * NCLASS;

    {
        uint4 z = make_uint4(0u, 0u, 0u, 0u);
        *(uint4*)&hist[tid * 8]     = z;
        *(uint4*)&hist[tid * 8 + 4] = z;
    }
    __syncthreads();

    // ---- pass 1: global uint4 (8 keys) -> LDS + histogram ----
    for (int i = tid; i < NCLASS / 8; i += 256) {       // 1250 groups
        uint4 v = *(const uint4*)(srow + i * 8);
        *(uint4*)(keys + i * 8) = v;
        unsigned int p[4] = {v.x, v.y, v.z, v.w};
        #pragma unroll
        for (int q = 0; q < 4; ++q) {
            atomicAdd(&hist[(p[q] & 0xFFFFu) >> 5], 1u);
            atomicAdd(&hist[(p[q] >> 16)     >> 5], 1u);
        }
    }
    __syncthreads();
    if (tid == 0) {
        unsigned int kl = keys[label];
        s_pos = key16val(kl);
        keys[label] = 0;          // phantom at bin 0; excluded below
        hist[kl >> 5] -= 1u;      // single thread between barriers: no race
    }
    __syncthreads();

    // ---- suffix scan over 2048 bins, registers only ----
    uint4 h0 = *(const uint4*)&hist[tid * 8];
    uint4 h1 = *(const uint4*)&hist[tid * 8 + 4];
    unsigned int v[8] = {h0.x, h0.y, h0.z, h0.w, h1.x, h1.y, h1.z, h1.w};
    unsigned int sfx[8];
    sfx[7] = v[7];
    #pragma unroll
    for (int i = 6; i >= 0; --i) sfx[i] = sfx[i + 1] + v[i];
    psum[tid] = sfx[0];
    __syncthreads();
    if (w == 0) {
        uint4 g = *(const uint4*)&psum[lane * 4];
        unsigned int gs = g.x + g.y + g.z + g.w;
        unsigned int s = gs;
        #pragma unroll
        for (int off = 1; off < 64; off <<= 1) {
            unsigned int o = __shfl_down(s, off);
            if (lane + off < 64) s += o;
        }
        unsigned int above = s - gs;       // partials in strictly-higher lanes
        unsigned int a3 = above;
        unsigned int a2 = a3 + g.w;
        unsigned int a1 = a2 + g.z;
        unsigned int a0 = a1 + g.y;
        psum[lane * 4 + 0] = a0; psum[lane * 4 + 1] = a1;
        psum[lane * 4 + 2] = a2; psum[lane * 4 + 3] = a3;
    }
    __syncthreads();
    {
        unsigned int add = psum[tid];      // keys in bins of threads > tid
        #pragma unroll
        for (int i = 0; i < 8; ++i) {
            unsigned int cur = sfx[i] + add;
            unsigned int nxt = ((i < 7) ? sfx[i + 1] : 0u) + add;
            if (cur >= KSEL && nxt < KSEL) {   // exactly one (tid,i) matches
                s_b    = (unsigned int)(tid * 8 + i);
                s_fill = KSEL - nxt;
                s_cntb = v[i];
            }
        }
    }
    __syncthreads();

    // ---- pass 2: exp-sum from LDS keys ----
    const unsigned int b = s_b;
    float sum = 0.f, bsum = 0.f;
    for (int i = tid; i < NCLASS / 8; i += 256) {
        uint4 pk = *(const uint4*)(keys + i * 8);
        unsigned int p[4] = {pk.x, pk.y, pk.z, pk.w};
        #pragma unroll
        for (int q = 0; q < 4; ++q) {
            unsigned int klo = p[q] & 0xFFFFu;
            unsigned int khi = p[q] >> 16;
            unsigned int blo = klo >> 5, bhi = khi >> 5;
            int idx = i * 8 + q * 2;
            if (blo >= b && idx != label) {
                float e = __expf(key16val(klo) - MLOG);
                if (blo > b) sum += e; else bsum += e;
            }
            if (bhi >= b && (idx + 1) != label) {
                float e = __expf(key16val(khi) - MLOG);
                if (bhi > b) sum += e; else bsum += e;
            }
        }
    }
    #pragma unroll
    for (int off = 32; off; off >>= 1) {
        sum  += __shfl_xor(sum, off);
        bsum += __shfl_xor(bsum, off);
    }
    if (lane == 0) { fred[w] = sum; fred[4 + w] = bsum; }
    __syncthreads();

    if (tid == 0) {
        float S  = fred[0] + fred[1] + fred[2] + fred[3];
        float Bs = fred[4] + fred[5] + fred[6] + fred[7];
        float ep = __expf(s_pos - MLOG);
        float denom = S + Bs * ((float)s_fill / (float)s_cntb) + ep;
        float p  = ep / denom;
        float ce = -logf(p + 1e-8f);
        float focal = 0.25f * (1.0f - p) * (1.0f - p) * ce;
        atomicAdd(out, focal * cw[label] * (1.0f / (float)BATCH));
    }
}

// ------------------------------------------------------------ launcher ------
extern "C" void kernel_launch(void* const* d_in, const int* in_sizes, int n_in,
                              void* d_out, int out_size, void* d_ws, size_t ws_size,
                              hipStream_t stream) {
    const float* emb    = (const float*)d_in[0];   // 4096 x 128
    const int*   labels = (const int*)d_in[1];     // 4096
    const float* cw     = (const float*)d_in[2];   // 10000
    const float* px     = (const float*)d_in[3];   // 10000 x 128
    float* out = (float*)d_out;
    char*  wsc = (char*)d_ws;

    unsigned short* px_bf  = (unsigned short*)wsc;               // 10000*128 bf16
    unsigned short* emb_bf = (unsigned short*)(wsc + 2560000);   // 4096*128 bf16
    unsigned short* simk   = (unsigned short*)(wsc + 3608576);   // chunk x 10000 key16

    size_t fixed = 3608576;
    size_t avail = (ws_size > fixed) ? (ws_size - fixed) : 0;
    long long cap = (long long)(avail / ((size_t)NCLASS * 2));
    int chunk = (int)((cap / 128) * 128);
    if (chunk > BATCH) chunk = BATCH;
    if (chunk < 128) chunk = 128;

    prep_kernel<<<3524, 256, 0, stream>>>(emb, px, px_bf, emb_bf, out);

    for (int r0 = 0; r0 < BATCH; r0 += chunk) {
        int rows = (BATCH - r0 < chunk) ? (BATCH - r0) : chunk;
        dim3 ggrid((NCLASS + 127) / 128, rows / 128);
        gemm_kernel<<<ggrid, 256, 0, stream>>>(emb_bf, px_bf, simk, r0);
        select_kernel<<<rows, 256, 0, stream>>>(simk, labels, cw, out, r0);
    }
}